// Round 15
// baseline (125.719 us; speedup 1.0000x reference)
//
#include <hip/hip_runtime.h>
#include <hip/hip_bf16.h>
#include <hip/hip_fp16.h>

#define NN 50000
#define NE 800000
// IN = OUT = 64, fan_in = 128
#define NBIN ((NN + 255) / 256)        // 196 coarse bins (dst>>8), 256 nodes each
#define PB ((NE + 1023) / 1024)        // 782 edge-tile blocks (1024 edges each)
#define GB ((NN + 63) / 64)            // 782 gemm blocks
#define MAXB 4864                      // max edges/bin

typedef __attribute__((ext_vector_type(8))) short bf16x8;
typedef __attribute__((ext_vector_type(4))) float f32x4;
typedef __attribute__((ext_vector_type(2))) float f32x2;

__device__ __forceinline__ unsigned int f2bf(float x) {
    unsigned int u = __float_as_uint(x);
    return (u + 0x7FFFu + ((u >> 16) & 1u)) >> 16;
}
__device__ __forceinline__ float bf2f(unsigned int b) {
    return __uint_as_float(b << 16);
}
// 4x fp8 e4m3 -> f32 via HW converts
__device__ __forceinline__ float4 f8x4_dec(unsigned int u) {
    f32x2 lo = __builtin_amdgcn_cvt_pk_f32_fp8(u, false);
    f32x2 hi = __builtin_amdgcn_cvt_pk_f32_fp8(u, true);
    float4 r; r.x = lo[0]; r.y = lo[1]; r.z = hi[0]; r.w = hi[1];
    return r;
}

// ---------------- MFMA GEMM core: 64 rows/block = 4 waves x 16-row M-tiles ----
// W is f32 row-major [K][OUTC]; converted to bf16 B-fragment order during staging.
// SRC 0: in=[X|H] (KC=4)   SRC 1: in=X (KC=2)   SRC 2: in=H*r (KC=2)
// OMODE 1: bf16 store  OMODE 2: bf16(acc + bf16 addH)  OMODE 3: fp8 e4m3 store
template <int OUTC, int KC, int SRC, int OMODE>
__device__ __forceinline__ void mgemm_core(
    const float* __restrict__ X, const float* __restrict__ Hm,
    const unsigned int* __restrict__ RUb, const float* __restrict__ Wsrc,
    const unsigned short* __restrict__ addH,
    unsigned short* __restrict__ outH, unsigned char* __restrict__ outF8,
    int bid, unsigned short* aS, unsigned short* wS)
{
    constexpr int NT = OUTC / 16;
    constexpr int WH = KC * NT * 64 * 8;            // halfwords
    const int tid = threadIdx.x;
    const int row0 = bid * 64;

    // stage W fragments: f32 [k][col] -> bf16 fragment order in LDS
    // frag idx i = ((kc*NT + n)*64 + l)*8 + j  <->  W[kc*32+(l>>4)*8+j][n*16+(l&15)]
    #pragma unroll 4
    for (int i = tid; i < WH; i += 256) {
        int j = i & 7, l = (i >> 3) & 63;
        int t = i >> 9;
        int n = t % NT, kc = t / NT;
        int k = kc * 32 + ((l >> 4) << 3) + j;
        int col = (n << 4) + (l & 15);
        wS[i] = (unsigned short)f2bf(Wsrc[k * OUTC + col]);
    }
    #pragma unroll
    for (int i = tid; i < 64 * KC * 8; i += 256) {
        int row = i / (KC * 8), f4 = i % (KC * 8);
        int g = row0 + row;
        float4 v = {0.f, 0.f, 0.f, 0.f};
        if (g < NN) {
            if (SRC == 0) {
                v = (f4 < 16) ? reinterpret_cast<const float4*>(X)[g * 16 + f4]
                              : reinterpret_cast<const float4*>(Hm)[g * 16 + f4 - 16];
            } else if (SRC == 1) {
                v = reinterpret_cast<const float4*>(X)[g * 16 + f4];
            } else {
                v = reinterpret_cast<const float4*>(Hm)[g * 16 + f4];
                unsigned int r0 = RUb[g * 64 + 2 * f4];
                unsigned int r1 = RUb[g * 64 + 2 * f4 + 1];
                v.x *= bf2f(r0 & 0xFFFFu); v.y *= bf2f(r0 >> 16);
                v.z *= bf2f(r1 & 0xFFFFu); v.w *= bf2f(r1 >> 16);
            }
        }
        int k = f4 * 4;
        int kc = k >> 5, ko = k & 31;
        int l = (row & 15) | ((ko >> 3) << 4);
        int j0 = ko & 7;
        int m = row >> 4;
        uint2 pk;
        pk.x = f2bf(v.x) | (f2bf(v.y) << 16);
        pk.y = f2bf(v.z) | (f2bf(v.w) << 16);
        *reinterpret_cast<uint2*>(aS + (((m * KC + kc) * 64 + l) * 8 + j0)) = pk;
    }
    __syncthreads();

    const int wid = tid >> 6, l = tid & 63;
    f32x4 acc[NT];
    #pragma unroll
    for (int n = 0; n < NT; ++n) acc[n] = {0.f, 0.f, 0.f, 0.f};

    const bf16x8* aF = reinterpret_cast<const bf16x8*>(aS);
    const bf16x8* wF = reinterpret_cast<const bf16x8*>(wS);
    #pragma unroll
    for (int kc = 0; kc < KC; ++kc) {
        bf16x8 a = aF[(wid * KC + kc) * 64 + l];
        #pragma unroll
        for (int n = 0; n < NT; ++n) {
            bf16x8 b = wF[(kc * NT + n) * 64 + l];
            acc[n] = __builtin_amdgcn_mfma_f32_16x16x32_bf16(a, b, acc[n], 0, 0, 0);
        }
    }

    // C/D layout: col = lane&15, row = (lane>>4)*4 + i   [m89-verified]
    const int rbase = row0 + wid * 16 + ((l >> 4) << 2);
    const int cl = l & 15;
    #pragma unroll
    for (int n = 0; n < NT; ++n) {
        #pragma unroll
        for (int i = 0; i < 4; ++i) {
            int row = rbase + i;
            if (row >= NN) continue;
            int col = n * 16 + cl;
            if (OMODE == 1) {
                outH[(size_t)row * OUTC + col] = (unsigned short)f2bf(acc[n][i]);
            } else if (OMODE == 2) {
                float a2 = acc[n][i] + bf2f(addH[(size_t)row * OUTC + col]);
                outH[(size_t)row * OUTC + col] = (unsigned short)f2bf(a2);
            } else {
                int q = __builtin_amdgcn_cvt_pk_fp8_f32(acc[n][i], acc[n][i], 0, false);
                outF8[(size_t)row * OUTC + col] = (unsigned char)(q & 0xFF);
            }
        }
    }
}

// ---------------- fused: coarse histogram (LDS only) || mfma-gemm1(fp8) || mfma-gemm2a ----
__launch_bounds__(256)
__global__ void k_build(const float* __restrict__ X, const float* __restrict__ Hm,
                        const float* __restrict__ W1, const float* __restrict__ W2,
                        unsigned char* __restrict__ Zf8, unsigned short* __restrict__ Z2p,
                        const int* __restrict__ dst, int* __restrict__ HT) {
    __shared__ unsigned short aS[8192];    // 16KB: A-fragments / hist[]
    __shared__ unsigned short wS[16384];   // 32KB: W-fragments
    const int bid = blockIdx.x;
    const int tid = threadIdx.x;
    if (bid < PB) {
        int* hist = reinterpret_cast<int*>(aS);
        for (int i = tid; i < NBIN; i += 256) hist[i] = 0;
        __syncthreads();
        const int base = bid * 1024 + tid;
        #pragma unroll
        for (int k = 0; k < 4; ++k) {
            int e = base + k * 256;
            if (e < NE) atomicAdd(&hist[dst[e] >> 8], 1);
        }
        __syncthreads();
        for (int i = tid; i < NBIN; i += 256) HT[i * PB + bid] = hist[i];
        return;
    }
    if (bid < PB + GB) {
        mgemm_core<128, 4, 0, 3>(X, Hm, nullptr, W1, nullptr,
                                 nullptr, Zf8, bid - PB, aS, wS);
        return;
    }
    mgemm_core<64, 2, 1, 1>(X, Hm, nullptr, W2, nullptr,
                            Z2p, nullptr, bid - PB - GB, aS, wS);
}

// ---------------- gemm2b: Z2b = bf16( Z2p + (H*r)@W2bot ) ----------------
__launch_bounds__(256)
__global__ void k_gemm2b(const float* __restrict__ X, const float* __restrict__ Hm,
                         const unsigned int* __restrict__ RUb,
                         const float* __restrict__ W2,
                         const unsigned short* __restrict__ Z2p,
                         unsigned short* __restrict__ Z2b) {
    __shared__ unsigned short aS[4096];    // 8KB
    __shared__ unsigned short wS[4096];    // 8KB
    mgemm_core<64, 2, 2, 2>(X, Hm, RUb, W2 + 64 * 64, Z2p, Z2b, nullptr,
                            blockIdx.x, aS, wS);
}

// ---------------- scanA1: per-bin exclusive scan over PB block counts ----------------
__launch_bounds__(256)
__global__ void k_scanA1(const int* __restrict__ HT, int* __restrict__ within,
                         int* __restrict__ binTot) {
    __shared__ int lds[PB];
    __shared__ int sc[256];
    __shared__ int carryS;
    const int b = blockIdx.x, tid = threadIdx.x;
    if (tid == 0) carryS = 0;
    for (int i = tid; i < PB; i += 256) lds[i] = HT[b * PB + i];
    __syncthreads();
    for (int c0 = 0; c0 < PB; c0 += 256) {
        int i = c0 + tid;
        int v = (i < PB) ? lds[i] : 0;
        sc[tid] = v;
        __syncthreads();
        #pragma unroll
        for (int off = 1; off < 256; off <<= 1) {
            int t = (tid >= off) ? sc[tid - off] : 0;
            __syncthreads();
            sc[tid] += t;
            __syncthreads();
        }
        int carry = carryS;
        if (i < PB) lds[i] = carry + sc[tid] - v;   // exclusive
        __syncthreads();
        if (tid == 255) carryS = carry + sc[255];
        __syncthreads();
    }
    for (int i = tid; i < PB; i += 256) within[b * PB + i] = lds[i];
    if (tid == 0) binTot[b] = carryS;
}

// ---------------- scatterA: group records by coarse bin (LDS cursors only) ----------------
__launch_bounds__(256)
__global__ void k_scatterA(const int* __restrict__ src, const int* __restrict__ dst,
                           const float* __restrict__ w, const int* __restrict__ binTot,
                           const int* __restrict__ within, uint2* __restrict__ rec) {
    __shared__ int bS[256];
    __shared__ int cur[NBIN];
    const int blk = blockIdx.x, tid = threadIdx.x;
    int bv = (tid < NBIN) ? binTot[tid] : 0;
    bS[tid] = bv;
    __syncthreads();
    #pragma unroll
    for (int off = 1; off < 256; off <<= 1) {
        int t = (tid >= off) ? bS[tid - off] : 0;
        __syncthreads();
        bS[tid] += t;
        __syncthreads();
    }
    if (tid < NBIN) cur[tid] = (bS[tid] - bv) + within[tid * PB + blk];
    __syncthreads();
    const int base = blk * 1024 + tid;
    #pragma unroll
    for (int k = 0; k < 4; ++k) {
        int e = base + k * 256;
        if (e < NE) {
            int d = dst[e];
            int pos = atomicAdd(&cur[d >> 8], 1);
            unsigned int hn = __half_as_ushort(__float2half(w[e]));
            uint2 r;
            r.x = (unsigned int)src[e] | (hn << 16);
            r.y = (unsigned int)d;
            rec[pos] = r;
        }
    }
}

// ---------------- phase2: per-bin sort -> snP (src|fp16 w), start, dinv ----------------
__launch_bounds__(256)
__global__ void k_phase2(const uint2* __restrict__ rec, const int* __restrict__ binTot,
                         unsigned int* __restrict__ snP, int* __restrict__ start,
                         float* __restrict__ dinv) {
    __shared__ unsigned int rSn[MAXB];
    __shared__ unsigned char rLo[MAXB];
    __shared__ unsigned int outSn[MAXB];
    __shared__ int cnt[256];
    __shared__ int sc[256];
    __shared__ int lstart[256];
    __shared__ int cur[256];
    const int b = blockIdx.x, tid = threadIdx.x;

    // bin offsets from binTot (inclusive scan)
    int bv = (tid < NBIN) ? binTot[tid] : 0;
    sc[tid] = bv;
    __syncthreads();
    #pragma unroll
    for (int off = 1; off < 256; off <<= 1) {
        int t = (tid >= off) ? sc[tid - off] : 0;
        __syncthreads();
        sc[tid] += t;
        __syncthreads();
    }
    const int e0 = (b == 0) ? 0 : sc[b - 1];
    int nE = sc[b] - e0;
    __syncthreads();
    if (nE > MAXB) nE = MAXB;   // statistically impossible; avoids LDS OOB

    cnt[tid] = 0;
    __syncthreads();
    for (int i = tid; i < nE; i += 256) {
        uint2 r = rec[e0 + i];
        rSn[i] = r.x;
        int lo = r.y & 255;
        rLo[i] = (unsigned char)lo;
        atomicAdd(&cnt[lo], 1);
    }
    __syncthreads();
    sc[tid] = cnt[tid];
    __syncthreads();
    #pragma unroll
    for (int off = 1; off < 256; off <<= 1) {
        int t = (tid >= off) ? sc[tid - off] : 0;
        __syncthreads();
        sc[tid] += t;
        __syncthreads();
    }
    lstart[tid] = sc[tid] - cnt[tid];
    cur[tid] = sc[tid] - cnt[tid];
    __syncthreads();
    const int node = b * 256 + tid;
    if (node <= NN) start[node] = e0 + lstart[tid];
    for (int i = tid; i < nE; i += 256) {
        int p = atomicAdd(&cur[rLo[i]], 1);
        outSn[p] = rSn[i];
    }
    __syncthreads();
    for (int i = tid; i < nE; i += 256) snP[e0 + i] = outSn[i];
    {
        int s0 = lstart[tid], c = cnt[tid];
        float sum = 0.f;
        for (int i = s0; i < s0 + c; ++i)
            sum += __half2float(__ushort_as_half((unsigned short)(outSn[i] >> 16)));
        if (node < NN) dinv[node] = rsqrtf(1.0f + sum);
    }
}

// ---------------- gather1 (fp8 Z1 unscaled): RU = bf16(sigmoid(dv_d*acc + b1)) ----
// acc = dv_d*Z[d] + sum_e (dinv[s_e]*w_e)*Z[s_e]
__launch_bounds__(256)
__global__ void k_gather1(const int* __restrict__ start, const unsigned int* __restrict__ snP,
                          const unsigned int* __restrict__ Zf8, const float* __restrict__ dinv,
                          const float* __restrict__ bias, uint2* __restrict__ RUb2) {
    const int node = blockIdx.x * 8 + (threadIdx.x >> 5);
    const int l = threadIdx.x & 31;
    if (node >= NN) return;

    const int e0 = start[node], e1 = start[node + 1];
    const float dvd = dinv[node];
    float4 acc = f8x4_dec(Zf8[(size_t)node * 32 + l]);
    acc.x *= dvd; acc.y *= dvd; acc.z *= dvd; acc.w *= dvd;

    #define EFMA8(U, NM) { float4 zz = f8x4_dec(U); \
        acc.x += zz.x * (NM); acc.y += zz.y * (NM); \
        acc.z += zz.z * (NM); acc.w += zz.w * (NM); }
    #define NMOF(SN) (dinv[(SN) & 0xFFFFu] * \
        __half2float(__ushort_as_half((unsigned short)((SN) >> 16))))

    int e = e0;
    for (; e + 8 <= e1; e += 8) {
        unsigned sn0 = snP[e],     sn1 = snP[e + 1], sn2 = snP[e + 2], sn3 = snP[e + 3];
        unsigned sn4 = snP[e + 4], sn5 = snP[e + 5], sn6 = snP[e + 6], sn7 = snP[e + 7];
        unsigned z0 = Zf8[(size_t)(sn0 & 0xFFFFu) * 32 + l];
        unsigned z1 = Zf8[(size_t)(sn1 & 0xFFFFu) * 32 + l];
        unsigned z2 = Zf8[(size_t)(sn2 & 0xFFFFu) * 32 + l];
        unsigned z3 = Zf8[(size_t)(sn3 & 0xFFFFu) * 32 + l];
        unsigned z4 = Zf8[(size_t)(sn4 & 0xFFFFu) * 32 + l];
        unsigned z5 = Zf8[(size_t)(sn5 & 0xFFFFu) * 32 + l];
        unsigned z6 = Zf8[(size_t)(sn6 & 0xFFFFu) * 32 + l];
        unsigned z7 = Zf8[(size_t)(sn7 & 0xFFFFu) * 32 + l];
        float n0 = NMOF(sn0), n1 = NMOF(sn1), n2 = NMOF(sn2), n3 = NMOF(sn3);
        float n4 = NMOF(sn4), n5 = NMOF(sn5), n6 = NMOF(sn6), n7 = NMOF(sn7);
        EFMA8(z0, n0) EFMA8(z1, n1) EFMA8(z2, n2) EFMA8(z3, n3)
        EFMA8(z4, n4) EFMA8(z5, n5) EFMA8(z6, n6) EFMA8(z7, n7)
    }
    if (e + 4 <= e1) {
        unsigned sn0 = snP[e], sn1 = snP[e + 1], sn2 = snP[e + 2], sn3 = snP[e + 3];
        unsigned z0 = Zf8[(size_t)(sn0 & 0xFFFFu) * 32 + l];
        unsigned z1 = Zf8[(size_t)(sn1 & 0xFFFFu) * 32 + l];
        unsigned z2 = Zf8[(size_t)(sn2 & 0xFFFFu) * 32 + l];
        unsigned z3 = Zf8[(size_t)(sn3 & 0xFFFFu) * 32 + l];
        float n0 = NMOF(sn0), n1 = NMOF(sn1), n2 = NMOF(sn2), n3 = NMOF(sn3);
        EFMA8(z0, n0) EFMA8(z1, n1) EFMA8(z2, n2) EFMA8(z3, n3)
        e += 4;
    }
    for (; e < e1; ++e) {
        unsigned sn = snP[e];
        unsigned z = Zf8[(size_t)(sn & 0xFFFFu) * 32 + l];
        float nm = NMOF(sn);
        EFMA8(z, nm)
    }
    #undef EFMA8
    #undef NMOF

    const int c = l * 4;
    float4 bb = *reinterpret_cast<const float4*>(bias + c);
    acc.x = acc.x * dvd + bb.x; acc.y = acc.y * dvd + bb.y;
    acc.z = acc.z * dvd + bb.z; acc.w = acc.w * dvd + bb.w;

    float4 o;
    o.x = 1.f / (1.f + expf(-acc.x));
    o.y = 1.f / (1.f + expf(-acc.y));
    o.z = 1.f / (1.f + expf(-acc.z));
    o.w = 1.f / (1.f + expf(-acc.w));
    uint2 pk;
    pk.x = f2bf(o.x) | (f2bf(o.y) << 16);
    pk.y = f2bf(o.z) | (f2bf(o.w) << 16);
    RUb2[(size_t)node * 32 + l] = pk;
}

// ---------------- gather2 (bf16 Z2 unscaled): out = u*H + (1-u)*tanh(dv_d*acc + b2) ----
__launch_bounds__(256)
__global__ void k_gather2(const int* __restrict__ start, const unsigned int* __restrict__ snP,
                          const uint2* __restrict__ Zb, const float* __restrict__ dinv,
                          const float* __restrict__ bias, const uint2* __restrict__ RUb2,
                          const float* __restrict__ Hm, float* __restrict__ out) {
    constexpr int GRP = 16;
    const int node = blockIdx.x * 16 + threadIdx.x / GRP;
    const int l = threadIdx.x % GRP;
    if (node >= NN) return;

    const int e0 = start[node], e1 = start[node + 1];
    const float dvd = dinv[node];

    uint2 zs = Zb[(size_t)node * GRP + l];
    float4 acc;
    acc.x = bf2f(zs.x & 0xFFFFu) * dvd;
    acc.y = bf2f(zs.x >> 16) * dvd;
    acc.z = bf2f(zs.y & 0xFFFFu) * dvd;
    acc.w = bf2f(zs.y >> 16) * dvd;

    #define EFMA(Z, NM) \
        acc.x += bf2f((Z).x & 0xFFFFu) * (NM); \
        acc.y += bf2f((Z).x >> 16) * (NM);     \
        acc.z += bf2f((Z).y & 0xFFFFu) * (NM); \
        acc.w += bf2f((Z).y >> 16) * (NM);
    #define NMOF(SN) (dinv[(SN) & 0xFFFFu] * \
        __half2float(__ushort_as_half((unsigned short)((SN) >> 16))))

    int e = e0;
    for (; e + 8 <= e1; e += 8) {
        unsigned sn0 = snP[e],     sn1 = snP[e + 1], sn2 = snP[e + 2], sn3 = snP[e + 3];
        unsigned sn4 = snP[e + 4], sn5 = snP[e + 5], sn6 = snP[e + 6], sn7 = snP[e + 7];
        uint2 z0 = Zb[(size_t)(sn0 & 0xFFFFu) * GRP + l];
        uint2 z1 = Zb[(size_t)(sn1 & 0xFFFFu) * GRP + l];
        uint2 z2 = Zb[(size_t)(sn2 & 0xFFFFu) * GRP + l];
        uint2 z3 = Zb[(size_t)(sn3 & 0xFFFFu) * GRP + l];
        uint2 z4 = Zb[(size_t)(sn4 & 0xFFFFu) * GRP + l];
        uint2 z5 = Zb[(size_t)(sn5 & 0xFFFFu) * GRP + l];
        uint2 z6 = Zb[(size_t)(sn6 & 0xFFFFu) * GRP + l];
        uint2 z7 = Zb[(size_t)(sn7 & 0xFFFFu) * GRP + l];
        float n0 = NMOF(sn0), n1 = NMOF(sn1), n2 = NMOF(sn2), n3 = NMOF(sn3);
        float n4 = NMOF(sn4), n5 = NMOF(sn5), n6 = NMOF(sn6), n7 = NMOF(sn7);
        EFMA(z0, n0) EFMA(z1, n1) EFMA(z2, n2) EFMA(z3, n3)
        EFMA(z4, n4) EFMA(z5, n5) EFMA(z6, n6) EFMA(z7, n7)
    }
    if (e + 4 <= e1) {
        unsigned sn0 = snP[e], sn1 = snP[e + 1], sn2 = snP[e + 2], sn3 = snP[e + 3];
        uint2 z0 = Zb[(size_t)(sn0 & 0xFFFFu) * GRP + l];
        uint2 z1 = Zb[(size_t)(sn1 & 0xFFFFu) * GRP + l];
        uint2 z2 = Zb[(size_t)(sn2 & 0xFFFFu) * GRP + l];
        uint2 z3 = Zb[(size_t)(sn3 & 0xFFFFu) * GRP + l];
        float n0 = NMOF(sn0), n1 = NMOF(sn1), n2 = NMOF(sn2), n3 = NMOF(sn3);
        EFMA(z0, n0) EFMA(z1, n1) EFMA(z2, n2) EFMA(z3, n3)
        e += 4;
    }
    for (; e < e1; ++e) {
        unsigned sn = snP[e];
        uint2 z = Zb[(size_t)(sn & 0xFFFFu) * GRP + l];
        float nm = NMOF(sn);
        EFMA(z, nm)
    }
    #undef EFMA
    #undef NMOF

    const int c = l * 4;
    float4 bb = *reinterpret_cast<const float4*>(bias + c);
    acc.x = acc.x * dvd + bb.x; acc.y = acc.y * dvd + bb.y;
    acc.z = acc.z * dvd + bb.z; acc.w = acc.w * dvd + bb.w;

    uint2 uu = RUb2[(size_t)node * 32 + 16 + l];
    float u0 = bf2f(uu.x & 0xFFFFu), u1 = bf2f(uu.x >> 16);
    float u2 = bf2f(uu.y & 0xFFFFu), u3 = bf2f(uu.y >> 16);
    float4 h4 = *reinterpret_cast<const float4*>(Hm + (size_t)node * 64 + c);
    float4 o;
    o.x = u0 * h4.x + (1.f - u0) * tanhf(acc.x);
    o.y = u1 * h4.y + (1.f - u1) * tanhf(acc.y);
    o.z = u2 * h4.z + (1.f - u2) * tanhf(acc.z);
    o.w = u3 * h4.w + (1.f - u3) * tanhf(acc.w);
    *reinterpret_cast<float4*>(out + (size_t)node * 64 + c) = o;
}

extern "C" void kernel_launch(void* const* d_in, const int* in_sizes, int n_in,
                              void* d_out, int out_size, void* d_ws, size_t ws_size,
                              hipStream_t stream) {
    const float* X  = (const float*)d_in[0];
    const float* Hm = (const float*)d_in[1];
    const int*   ei = (const int*)d_in[2];           // [2][E]
    const float* w  = (const float*)d_in[3];
    const float* W1 = (const float*)d_in[4];         // [128][128]
    const float* b1 = (const float*)d_in[5];
    const float* W2 = (const float*)d_in[6];         // [128][64]
    const float* b2 = (const float*)d_in[7];
    float* out = (float*)d_out;

    const int* src = ei;
    const int* dst = ei + NE;

    // 8B-aligned chunks first
    char* p = (char*)d_ws;
    uint2* rec   = (uint2*)p;  p += sizeof(uint2) * NE;            // 6.4MB
    uint2* Z2b   = (uint2*)p;  p += sizeof(uint2) * NN * 16;       // NN x 64 bf16
    uint2* RUb2  = (uint2*)p;  p += sizeof(uint2) * NN * 32;       // NN x 128 bf16
    unsigned short* Z2p = (unsigned short*)p; p += sizeof(unsigned short) * NN * 64; // bf16
    float* dinv  = (float*)p;  p += sizeof(float) * NN;
    int*   start = (int*)p;    p += sizeof(int) * (NN + 1);
    int*   binTot   = (int*)p; p += sizeof(int) * (NBIN + 1);
    int*   HT       = (int*)p; p += sizeof(int) * NBIN * PB;
    int*   within   = (int*)p; p += sizeof(int) * NBIN * PB;
    unsigned int* snP = (unsigned int*)p; p += sizeof(unsigned int) * NE;
    unsigned int* Zf8 = (unsigned int*)p; p += sizeof(unsigned int) * NN * 32;  // NN x 128 fp8

    // fused: coarse histogram (LDS only) || mfma gemm1 (fp8 out) || mfma gemm2a (bf16)
    // (W converted to fragment order in-kernel; no wprep launch)
    k_build<<<PB + 2 * GB, 256, 0, stream>>>(X, Hm, W1, W2,
                                             (unsigned char*)Zf8, Z2p, dst, HT);

    // CSR via two-level counting sort
    k_scanA1<<<NBIN, 256, 0, stream>>>(HT, within, binTot);
    k_scatterA<<<PB, 256, 0, stream>>>(src, dst, w, binTot, within, rec);
    k_phase2<<<NBIN, 256, 0, stream>>>(rec, binTot, snP, start, dinv);

    // conv1 aggregate (fp8 gather, inline norm): RU = sigmoid(...)
    k_gather1<<<(NN + 7) / 8, 256, 0, stream>>>(start, snP, Zf8, dinv, b1, RUb2);

    // conv2: Z2b = bf16(Z2p + (H*r)@W2bot) ; out = u*H + (1-u)*tanh(...)
    k_gemm2b<<<GB, 256, 0, stream>>>(X, Hm, (const unsigned int*)RUb2, W2, Z2p,
                                     (unsigned short*)Z2b);
    k_gather2<<<(NN + 15) / 16, 256, 0, stream>>>(start, snP, Z2b, dinv, b2, RUb2, Hm, out);
}

// Round 16
// 113.108 us; speedup vs baseline: 1.1115x; 1.1115x over previous
//
#include <hip/hip_runtime.h>
#include <hip/hip_bf16.h>
#include <hip/hip_fp16.h>

#define NN 50000
#define NE 800000
// IN = OUT = 64, fan_in = 128
#define NBIN ((NN + 255) / 256)        // 196 coarse bins (dst>>8), 256 nodes each
#define PB ((NE + 1023) / 1024)        // 782 edge-tile blocks (1024 edges each)
#define GB ((NN + 63) / 64)            // 782 gemm blocks
#define MAXB 4864                      // max edges/bin

typedef __attribute__((ext_vector_type(8))) short bf16x8;
typedef __attribute__((ext_vector_type(4))) float f32x4;
typedef __attribute__((ext_vector_type(2))) float f32x2;

__device__ __forceinline__ unsigned int f2bf(float x) {
    unsigned int u = __float_as_uint(x);
    return (u + 0x7FFFu + ((u >> 16) & 1u)) >> 16;
}
__device__ __forceinline__ float bf2f(unsigned int b) {
    return __uint_as_float(b << 16);
}
// 4x fp8 e4m3 -> f32 via HW converts
__device__ __forceinline__ float4 f8x4_dec(unsigned int u) {
    f32x2 lo = __builtin_amdgcn_cvt_pk_f32_fp8(u, false);
    f32x2 hi = __builtin_amdgcn_cvt_pk_f32_fp8(u, true);
    float4 r; r.x = lo[0]; r.y = lo[1]; r.z = hi[0]; r.w = hi[1];
    return r;
}

// ---------------- W fragment precompute (B-operand layout for mfma 16x16x32) ----
__global__ void k_wprep(const float* __restrict__ W1, const float* __restrict__ W2,
                        unsigned short* __restrict__ Wf1,
                        unsigned short* __restrict__ Wf2t,
                        unsigned short* __restrict__ Wf2b) {
    int i = blockIdx.x * 256 + threadIdx.x;
    if (i < 16384) {   // W1: K=128 (kc 0..3), OUTC=128 (n 0..7)
        int j = i & 7, l = (i >> 3) & 63, n = (i >> 9) & 7, kc = i >> 12;
        int k = kc * 32 + ((l >> 4) << 3) + j;
        int col = (n << 4) + (l & 15);
        Wf1[i] = (unsigned short)f2bf(W1[k * 128 + col]);
    }
    if (i < 4096) {    // W2 top/bottom: K=64 (kc 0..1), OUTC=64 (n 0..3)
        int j = i & 7, l = (i >> 3) & 63, n = (i >> 9) & 3, kc = i >> 11;
        int k = kc * 32 + ((l >> 4) << 3) + j;
        int col = (n << 4) + (l & 15);
        Wf2t[i] = (unsigned short)f2bf(W2[k * 64 + col]);
        Wf2b[i] = (unsigned short)f2bf(W2[(k + 64) * 64 + col]);
    }
}

// ---------------- MFMA GEMM core: 64 rows/block = 4 waves x 16-row M-tiles ----
// SRC 0: in=[X|H] (KC=4)   SRC 1: in=X (KC=2)   SRC 2: in=H*r (KC=2)
// OMODE 1: bf16 store  OMODE 2: bf16(acc + bf16 addH)  OMODE 3: fp8 e4m3 store
template <int OUTC, int KC, int SRC, int OMODE>
__device__ __forceinline__ void mgemm_core(
    const float* __restrict__ X, const float* __restrict__ Hm,
    const unsigned int* __restrict__ RUb, const unsigned short* __restrict__ Wf,
    const unsigned short* __restrict__ addH,
    unsigned short* __restrict__ outH, unsigned char* __restrict__ outF8,
    int bid, unsigned short* aS, unsigned short* wS)
{
    constexpr int NT = OUTC / 16;
    constexpr int WH = KC * NT * 64 * 8;            // halfwords
    const int tid = threadIdx.x;
    const int row0 = bid * 64;

    // stage pre-formatted W fragments: coalesced 16B copies
    {
        const uint4* Wg4 = reinterpret_cast<const uint4*>(Wf);
        uint4* wS4 = reinterpret_cast<uint4*>(wS);
        #pragma unroll
        for (int i = tid; i < WH / 8; i += 256) wS4[i] = Wg4[i];
    }
    #pragma unroll
    for (int i = tid; i < 64 * KC * 8; i += 256) {
        int row = i / (KC * 8), f4 = i % (KC * 8);
        int g = row0 + row;
        float4 v = {0.f, 0.f, 0.f, 0.f};
        if (g < NN) {
            if (SRC == 0) {
                v = (f4 < 16) ? reinterpret_cast<const float4*>(X)[g * 16 + f4]
                              : reinterpret_cast<const float4*>(Hm)[g * 16 + f4 - 16];
            } else if (SRC == 1) {
                v = reinterpret_cast<const float4*>(X)[g * 16 + f4];
            } else {
                v = reinterpret_cast<const float4*>(Hm)[g * 16 + f4];
                unsigned int r0 = RUb[g * 64 + 2 * f4];
                unsigned int r1 = RUb[g * 64 + 2 * f4 + 1];
                v.x *= bf2f(r0 & 0xFFFFu); v.y *= bf2f(r0 >> 16);
                v.z *= bf2f(r1 & 0xFFFFu); v.w *= bf2f(r1 >> 16);
            }
        }
        int k = f4 * 4;
        int kc = k >> 5, ko = k & 31;
        int l = (row & 15) | ((ko >> 3) << 4);
        int j0 = ko & 7;
        int m = row >> 4;
        uint2 pk;
        pk.x = f2bf(v.x) | (f2bf(v.y) << 16);
        pk.y = f2bf(v.z) | (f2bf(v.w) << 16);
        *reinterpret_cast<uint2*>(aS + (((m * KC + kc) * 64 + l) * 8 + j0)) = pk;
    }
    __syncthreads();

    const int wid = tid >> 6, l = tid & 63;
    f32x4 acc[NT];
    #pragma unroll
    for (int n = 0; n < NT; ++n) acc[n] = {0.f, 0.f, 0.f, 0.f};

    const bf16x8* aF = reinterpret_cast<const bf16x8*>(aS);
    const bf16x8* wF = reinterpret_cast<const bf16x8*>(wS);
    #pragma unroll
    for (int kc = 0; kc < KC; ++kc) {
        bf16x8 a = aF[(wid * KC + kc) * 64 + l];
        #pragma unroll
        for (int n = 0; n < NT; ++n) {
            bf16x8 b = wF[(kc * NT + n) * 64 + l];
            acc[n] = __builtin_amdgcn_mfma_f32_16x16x32_bf16(a, b, acc[n], 0, 0, 0);
        }
    }

    // C/D layout: col = lane&15, row = (lane>>4)*4 + i   [m89-verified]
    const int rbase = row0 + wid * 16 + ((l >> 4) << 2);
    const int cl = l & 15;
    #pragma unroll
    for (int n = 0; n < NT; ++n) {
        #pragma unroll
        for (int i = 0; i < 4; ++i) {
            int row = rbase + i;
            if (row >= NN) continue;
            int col = n * 16 + cl;
            if (OMODE == 1) {
                outH[(size_t)row * OUTC + col] = (unsigned short)f2bf(acc[n][i]);
            } else if (OMODE == 2) {
                float a2 = acc[n][i] + bf2f(addH[(size_t)row * OUTC + col]);
                outH[(size_t)row * OUTC + col] = (unsigned short)f2bf(a2);
            } else {
                int q = __builtin_amdgcn_cvt_pk_fp8_f32(acc[n][i], acc[n][i], 0, false);
                outF8[(size_t)row * OUTC + col] = (unsigned char)(q & 0xFF);
            }
        }
    }
}

// ---------------- fused: coarse histogram (LDS only) || mfma-gemm1(fp8) || mfma-gemm2a ----
__launch_bounds__(256)
__global__ void k_build(const float* __restrict__ X, const float* __restrict__ Hm,
                        const unsigned short* __restrict__ Wf1,
                        const unsigned short* __restrict__ Wf2t,
                        unsigned char* __restrict__ Zf8, unsigned short* __restrict__ Z2p,
                        const int* __restrict__ dst, int* __restrict__ HT) {
    __shared__ unsigned short aS[8192];    // 16KB: A-fragments / hist[]
    __shared__ unsigned short wS[16384];   // 32KB: W-fragments
    const int bid = blockIdx.x;
    const int tid = threadIdx.x;
    if (bid < PB) {
        int* hist = reinterpret_cast<int*>(aS);
        for (int i = tid; i < NBIN; i += 256) hist[i] = 0;
        __syncthreads();
        const int base = bid * 1024 + tid;
        #pragma unroll
        for (int k = 0; k < 4; ++k) {
            int e = base + k * 256;
            if (e < NE) atomicAdd(&hist[dst[e] >> 8], 1);
        }
        __syncthreads();
        for (int i = tid; i < NBIN; i += 256) HT[i * PB + bid] = hist[i];
        return;
    }
    if (bid < PB + GB) {
        mgemm_core<128, 4, 0, 3>(X, Hm, nullptr, Wf1, nullptr,
                                 nullptr, Zf8, bid - PB, aS, wS);
        return;
    }
    mgemm_core<64, 2, 1, 1>(X, Hm, nullptr, Wf2t, nullptr,
                            Z2p, nullptr, bid - PB - GB, aS, wS);
}

// ---------------- gemm2b: Z2b = bf16( Z2p + (H*r)@W2bot ) ----------------
__launch_bounds__(256)
__global__ void k_gemm2b(const float* __restrict__ X, const float* __restrict__ Hm,
                         const unsigned int* __restrict__ RUb,
                         const unsigned short* __restrict__ Wf2b,
                         const unsigned short* __restrict__ Z2p,
                         unsigned short* __restrict__ Z2b) {
    __shared__ unsigned short aS[4096];    // 8KB
    __shared__ unsigned short wS[4096];    // 8KB
    mgemm_core<64, 2, 2, 2>(X, Hm, RUb, Wf2b, Z2p, Z2b, nullptr,
                            blockIdx.x, aS, wS);
}

// ---------------- scanA1: per-bin exclusive scan over PB block counts ----------------
__launch_bounds__(256)
__global__ void k_scanA1(const int* __restrict__ HT, int* __restrict__ within,
                         int* __restrict__ binTot) {
    __shared__ int lds[PB];
    __shared__ int sc[256];
    __shared__ int carryS;
    const int b = blockIdx.x, tid = threadIdx.x;
    if (tid == 0) carryS = 0;
    for (int i = tid; i < PB; i += 256) lds[i] = HT[b * PB + i];
    __syncthreads();
    for (int c0 = 0; c0 < PB; c0 += 256) {
        int i = c0 + tid;
        int v = (i < PB) ? lds[i] : 0;
        sc[tid] = v;
        __syncthreads();
        #pragma unroll
        for (int off = 1; off < 256; off <<= 1) {
            int t = (tid >= off) ? sc[tid - off] : 0;
            __syncthreads();
            sc[tid] += t;
            __syncthreads();
        }
        int carry = carryS;
        if (i < PB) lds[i] = carry + sc[tid] - v;   // exclusive
        __syncthreads();
        if (tid == 255) carryS = carry + sc[255];
        __syncthreads();
    }
    for (int i = tid; i < PB; i += 256) within[b * PB + i] = lds[i];
    if (tid == 0) binTot[b] = carryS;
}

// ---------------- scatterA: group records by coarse bin (LDS cursors only) ----------------
__launch_bounds__(256)
__global__ void k_scatterA(const int* __restrict__ src, const int* __restrict__ dst,
                           const float* __restrict__ w, const int* __restrict__ binTot,
                           const int* __restrict__ within, uint2* __restrict__ rec) {
    __shared__ int bS[256];
    __shared__ int cur[NBIN];
    const int blk = blockIdx.x, tid = threadIdx.x;
    int bv = (tid < NBIN) ? binTot[tid] : 0;
    bS[tid] = bv;
    __syncthreads();
    #pragma unroll
    for (int off = 1; off < 256; off <<= 1) {
        int t = (tid >= off) ? bS[tid - off] : 0;
        __syncthreads();
        bS[tid] += t;
        __syncthreads();
    }
    if (tid < NBIN) cur[tid] = (bS[tid] - bv) + within[tid * PB + blk];
    __syncthreads();
    const int base = blk * 1024 + tid;
    #pragma unroll
    for (int k = 0; k < 4; ++k) {
        int e = base + k * 256;
        if (e < NE) {
            int d = dst[e];
            int pos = atomicAdd(&cur[d >> 8], 1);
            unsigned int hn = __half_as_ushort(__float2half(w[e]));
            uint2 r;
            r.x = (unsigned int)src[e] | (hn << 16);
            r.y = (unsigned int)d;
            rec[pos] = r;
        }
    }
}

// ---------------- phase2: per-bin sort -> snP (src|fp16 w), start, dinv ----------------
__launch_bounds__(256)
__global__ void k_phase2(const uint2* __restrict__ rec, const int* __restrict__ binTot,
                         unsigned int* __restrict__ snP, int* __restrict__ start,
                         float* __restrict__ dinv) {
    __shared__ unsigned int rSn[MAXB];
    __shared__ unsigned char rLo[MAXB];
    __shared__ unsigned int outSn[MAXB];
    __shared__ int cnt[256];
    __shared__ int sc[256];
    __shared__ int lstart[256];
    __shared__ int cur[256];
    const int b = blockIdx.x, tid = threadIdx.x;

    // bin offsets from binTot (inclusive scan)
    int bv = (tid < NBIN) ? binTot[tid] : 0;
    sc[tid] = bv;
    __syncthreads();
    #pragma unroll
    for (int off = 1; off < 256; off <<= 1) {
        int t = (tid >= off) ? sc[tid - off] : 0;
        __syncthreads();
        sc[tid] += t;
        __syncthreads();
    }
    const int e0 = (b == 0) ? 0 : sc[b - 1];
    int nE = sc[b] - e0;
    __syncthreads();
    if (nE > MAXB) nE = MAXB;   // statistically impossible; avoids LDS OOB

    cnt[tid] = 0;
    __syncthreads();
    for (int i = tid; i < nE; i += 256) {
        uint2 r = rec[e0 + i];
        rSn[i] = r.x;
        int lo = r.y & 255;
        rLo[i] = (unsigned char)lo;
        atomicAdd(&cnt[lo], 1);
    }
    __syncthreads();
    sc[tid] = cnt[tid];
    __syncthreads();
    #pragma unroll
    for (int off = 1; off < 256; off <<= 1) {
        int t = (tid >= off) ? sc[tid - off] : 0;
        __syncthreads();
        sc[tid] += t;
        __syncthreads();
    }
    lstart[tid] = sc[tid] - cnt[tid];
    cur[tid] = sc[tid] - cnt[tid];
    __syncthreads();
    const int node = b * 256 + tid;
    if (node <= NN) start[node] = e0 + lstart[tid];
    for (int i = tid; i < nE; i += 256) {
        int p = atomicAdd(&cur[rLo[i]], 1);
        outSn[p] = rSn[i];
    }
    __syncthreads();
    for (int i = tid; i < nE; i += 256) snP[e0 + i] = outSn[i];
    {
        int s0 = lstart[tid], c = cnt[tid];
        float sum = 0.f;
        for (int i = s0; i < s0 + c; ++i)
            sum += __half2float(__ushort_as_half((unsigned short)(outSn[i] >> 16)));
        if (node < NN) dinv[node] = rsqrtf(1.0f + sum);
    }
}

// ---------------- gather1 (fp8 Z1 unscaled): RU = bf16(sigmoid(dv_d*acc + b1)) ----
// acc = dv_d*Z[d] + sum_e (dinv[s_e]*w_e)*Z[s_e]
__launch_bounds__(256)
__global__ void k_gather1(const int* __restrict__ start, const unsigned int* __restrict__ snP,
                          const unsigned int* __restrict__ Zf8, const float* __restrict__ dinv,
                          const float* __restrict__ bias, uint2* __restrict__ RUb2) {
    const int node = blockIdx.x * 8 + (threadIdx.x >> 5);
    const int l = threadIdx.x & 31;
    if (node >= NN) return;

    const int e0 = start[node], e1 = start[node + 1];
    const float dvd = dinv[node];
    float4 acc = f8x4_dec(Zf8[(size_t)node * 32 + l]);
    acc.x *= dvd; acc.y *= dvd; acc.z *= dvd; acc.w *= dvd;

    #define EFMA8(U, NM) { float4 zz = f8x4_dec(U); \
        acc.x += zz.x * (NM); acc.y += zz.y * (NM); \
        acc.z += zz.z * (NM); acc.w += zz.w * (NM); }
    #define NMOF(SN) (dinv[(SN) & 0xFFFFu] * \
        __half2float(__ushort_as_half((unsigned short)((SN) >> 16))))

    int e = e0;
    for (; e + 8 <= e1; e += 8) {
        unsigned sn0 = snP[e],     sn1 = snP[e + 1], sn2 = snP[e + 2], sn3 = snP[e + 3];
        unsigned sn4 = snP[e + 4], sn5 = snP[e + 5], sn6 = snP[e + 6], sn7 = snP[e + 7];
        unsigned z0 = Zf8[(size_t)(sn0 & 0xFFFFu) * 32 + l];
        unsigned z1 = Zf8[(size_t)(sn1 & 0xFFFFu) * 32 + l];
        unsigned z2 = Zf8[(size_t)(sn2 & 0xFFFFu) * 32 + l];
        unsigned z3 = Zf8[(size_t)(sn3 & 0xFFFFu) * 32 + l];
        unsigned z4 = Zf8[(size_t)(sn4 & 0xFFFFu) * 32 + l];
        unsigned z5 = Zf8[(size_t)(sn5 & 0xFFFFu) * 32 + l];
        unsigned z6 = Zf8[(size_t)(sn6 & 0xFFFFu) * 32 + l];
        unsigned z7 = Zf8[(size_t)(sn7 & 0xFFFFu) * 32 + l];
        float n0 = NMOF(sn0), n1 = NMOF(sn1), n2 = NMOF(sn2), n3 = NMOF(sn3);
        float n4 = NMOF(sn4), n5 = NMOF(sn5), n6 = NMOF(sn6), n7 = NMOF(sn7);
        EFMA8(z0, n0) EFMA8(z1, n1) EFMA8(z2, n2) EFMA8(z3, n3)
        EFMA8(z4, n4) EFMA8(z5, n5) EFMA8(z6, n6) EFMA8(z7, n7)
    }
    if (e + 4 <= e1) {
        unsigned sn0 = snP[e], sn1 = snP[e + 1], sn2 = snP[e + 2], sn3 = snP[e + 3];
        unsigned z0 = Zf8[(size_t)(sn0 & 0xFFFFu) * 32 + l];
        unsigned z1 = Zf8[(size_t)(sn1 & 0xFFFFu) * 32 + l];
        unsigned z2 = Zf8[(size_t)(sn2 & 0xFFFFu) * 32 + l];
        unsigned z3 = Zf8[(size_t)(sn3 & 0xFFFFu) * 32 + l];
        float n0 = NMOF(sn0), n1 = NMOF(sn1), n2 = NMOF(sn2), n3 = NMOF(sn3);
        EFMA8(z0, n0) EFMA8(z1, n1) EFMA8(z2, n2) EFMA8(z3, n3)
        e += 4;
    }
    for (; e < e1; ++e) {
        unsigned sn = snP[e];
        unsigned z = Zf8[(size_t)(sn & 0xFFFFu) * 32 + l];
        float nm = NMOF(sn);
        EFMA8(z, nm)
    }
    #undef EFMA8
    #undef NMOF

    const int c = l * 4;
    float4 bb = *reinterpret_cast<const float4*>(bias + c);
    acc.x = acc.x * dvd + bb.x; acc.y = acc.y * dvd + bb.y;
    acc.z = acc.z * dvd + bb.z; acc.w = acc.w * dvd + bb.w;

    float4 o;
    o.x = 1.f / (1.f + expf(-acc.x));
    o.y = 1.f / (1.f + expf(-acc.y));
    o.z = 1.f / (1.f + expf(-acc.z));
    o.w = 1.f / (1.f + expf(-acc.w));
    uint2 pk;
    pk.x = f2bf(o.x) | (f2bf(o.y) << 16);
    pk.y = f2bf(o.z) | (f2bf(o.w) << 16);
    RUb2[(size_t)node * 32 + l] = pk;
}

// ---------------- gather2 (bf16 Z2 unscaled): out = u*H + (1-u)*tanh(dv_d*acc + b2) ----
__launch_bounds__(256)
__global__ void k_gather2(const int* __restrict__ start, const unsigned int* __restrict__ snP,
                          const uint2* __restrict__ Zb, const float* __restrict__ dinv,
                          const float* __restrict__ bias, const uint2* __restrict__ RUb2,
                          const float* __restrict__ Hm, float* __restrict__ out) {
    constexpr int GRP = 16;
    const int node = blockIdx.x * 16 + threadIdx.x / GRP;
    const int l = threadIdx.x % GRP;
    if (node >= NN) return;

    const int e0 = start[node], e1 = start[node + 1];
    const float dvd = dinv[node];

    uint2 zs = Zb[(size_t)node * GRP + l];
    float4 acc;
    acc.x = bf2f(zs.x & 0xFFFFu) * dvd;
    acc.y = bf2f(zs.x >> 16) * dvd;
    acc.z = bf2f(zs.y & 0xFFFFu) * dvd;
    acc.w = bf2f(zs.y >> 16) * dvd;

    #define EFMA(Z, NM) \
        acc.x += bf2f((Z).x & 0xFFFFu) * (NM); \
        acc.y += bf2f((Z).x >> 16) * (NM);     \
        acc.z += bf2f((Z).y & 0xFFFFu) * (NM); \
        acc.w += bf2f((Z).y >> 16) * (NM);
    #define NMOF(SN) (dinv[(SN) & 0xFFFFu] * \
        __half2float(__ushort_as_half((unsigned short)((SN) >> 16))))

    int e = e0;
    for (; e + 8 <= e1; e += 8) {
        unsigned sn0 = snP[e],     sn1 = snP[e + 1], sn2 = snP[e + 2], sn3 = snP[e + 3];
        unsigned sn4 = snP[e + 4], sn5 = snP[e + 5], sn6 = snP[e + 6], sn7 = snP[e + 7];
        uint2 z0 = Zb[(size_t)(sn0 & 0xFFFFu) * GRP + l];
        uint2 z1 = Zb[(size_t)(sn1 & 0xFFFFu) * GRP + l];
        uint2 z2 = Zb[(size_t)(sn2 & 0xFFFFu) * GRP + l];
        uint2 z3 = Zb[(size_t)(sn3 & 0xFFFFu) * GRP + l];
        uint2 z4 = Zb[(size_t)(sn4 & 0xFFFFu) * GRP + l];
        uint2 z5 = Zb[(size_t)(sn5 & 0xFFFFu) * GRP + l];
        uint2 z6 = Zb[(size_t)(sn6 & 0xFFFFu) * GRP + l];
        uint2 z7 = Zb[(size_t)(sn7 & 0xFFFFu) * GRP + l];
        float n0 = NMOF(sn0), n1 = NMOF(sn1), n2 = NMOF(sn2), n3 = NMOF(sn3);
        float n4 = NMOF(sn4), n5 = NMOF(sn5), n6 = NMOF(sn6), n7 = NMOF(sn7);
        EFMA(z0, n0) EFMA(z1, n1) EFMA(z2, n2) EFMA(z3, n3)
        EFMA(z4, n4) EFMA(z5, n5) EFMA(z6, n6) EFMA(z7, n7)
    }
    if (e + 4 <= e1) {
        unsigned sn0 = snP[e], sn1 = snP[e + 1], sn2 = snP[e + 2], sn3 = snP[e + 3];
        uint2 z0 = Zb[(size_t)(sn0 & 0xFFFFu) * GRP + l];
        uint2 z1 = Zb[(size_t)(sn1 & 0xFFFFu) * GRP + l];
        uint2 z2 = Zb[(size_t)(sn2 & 0xFFFFu) * GRP + l];
        uint2 z3 = Zb[(size_t)(sn3 & 0xFFFFu) * GRP + l];
        float n0 = NMOF(sn0), n1 = NMOF(sn1), n2 = NMOF(sn2), n3 = NMOF(sn3);
        EFMA(z0, n0) EFMA(z1, n1) EFMA(z2, n2) EFMA(z3, n3)
        e += 4;
    }
    for (; e < e1; ++e) {
        unsigned sn = snP[e];
        uint2 z = Zb[(size_t)(sn & 0xFFFFu) * GRP + l];
        float nm = NMOF(sn);
        EFMA(z, nm)
    }
    #undef EFMA
    #undef NMOF

    const int c = l * 4;
    float4 bb = *reinterpret_cast<const float4*>(bias + c);
    acc.x = acc.x * dvd + bb.x; acc.y = acc.y * dvd + bb.y;
    acc.z = acc.z * dvd + bb.z; acc.w = acc.w * dvd + bb.w;

    uint2 uu = RUb2[(size_t)node * 32 + 16 + l];
    float u0 = bf2f(uu.x & 0xFFFFu), u1 = bf2f(uu.x >> 16);
    float u2 = bf2f(uu.y & 0xFFFFu), u3 = bf2f(uu.y >> 16);
    float4 h4 = *reinterpret_cast<const float4*>(Hm + (size_t)node * 64 + c);
    float4 o;
    o.x = u0 * h4.x + (1.f - u0) * tanhf(acc.x);
    o.y = u1 * h4.y + (1.f - u1) * tanhf(acc.y);
    o.z = u2 * h4.z + (1.f - u2) * tanhf(acc.z);
    o.w = u3 * h4.w + (1.f - u3) * tanhf(acc.w);
    *reinterpret_cast<float4*>(out + (size_t)node * 64 + c) = o;
}

extern "C" void kernel_launch(void* const* d_in, const int* in_sizes, int n_in,
                              void* d_out, int out_size, void* d_ws, size_t ws_size,
                              hipStream_t stream) {
    const float* X  = (const float*)d_in[0];
    const float* Hm = (const float*)d_in[1];
    const int*   ei = (const int*)d_in[2];           // [2][E]
    const float* w  = (const float*)d_in[3];
    const float* W1 = (const float*)d_in[4];         // [128][128]
    const float* b1 = (const float*)d_in[5];
    const float* W2 = (const float*)d_in[6];         // [128][64]
    const float* b2 = (const float*)d_in[7];
    float* out = (float*)d_out;

    const int* src = ei;
    const int* dst = ei + NE;

    // 8B-aligned chunks first
    char* p = (char*)d_ws;
    uint2* rec   = (uint2*)p;  p += sizeof(uint2) * NE;            // 6.4MB
    uint2* Z2b   = (uint2*)p;  p += sizeof(uint2) * NN * 16;       // NN x 64 bf16
    uint2* RUb2  = (uint2*)p;  p += sizeof(uint2) * NN * 32;       // NN x 128 bf16
    unsigned short* Z2p = (unsigned short*)p; p += sizeof(unsigned short) * NN * 64; // bf16
    float* dinv  = (float*)p;  p += sizeof(float) * NN;
    int*   start = (int*)p;    p += sizeof(int) * (NN + 1);
    int*   binTot   = (int*)p; p += sizeof(int) * (NBIN + 1);
    int*   HT       = (int*)p; p += sizeof(int) * NBIN * PB;
    int*   within   = (int*)p; p += sizeof(int) * NBIN * PB;
    unsigned int* snP = (unsigned int*)p; p += sizeof(unsigned int) * NE;
    unsigned int* Zf8 = (unsigned int*)p; p += sizeof(unsigned int) * NN * 32;  // NN x 128 fp8
    unsigned short* Wf1  = (unsigned short*)p; p += sizeof(unsigned short) * 16384;
    unsigned short* Wf2t = (unsigned short*)p; p += sizeof(unsigned short) * 4096;
    unsigned short* Wf2b = (unsigned short*)p; p += sizeof(unsigned short) * 4096;

    // W fragments (tiny, coalesced staging downstream)
    k_wprep<<<64, 256, 0, stream>>>(W1, W2, Wf1, Wf2t, Wf2b);

    // fused: coarse histogram (LDS only) || mfma gemm1 (fp8 out) || mfma gemm2a (bf16)
    k_build<<<PB + 2 * GB, 256, 0, stream>>>(X, Hm, Wf1, Wf2t,
                                             (unsigned char*)Zf8, Z2p, dst, HT);

    // CSR via two-level counting sort
    k_scanA1<<<NBIN, 256, 0, stream>>>(HT, within, binTot);
    k_scatterA<<<PB, 256, 0, stream>>>(src, dst, w, binTot, within, rec);
    k_phase2<<<NBIN, 256, 0, stream>>>(rec, binTot, snP, start, dinv);

    // conv1 aggregate (fp8 gather, inline norm): RU = sigmoid(...)
    k_gather1<<<(NN + 7) / 8, 256, 0, stream>>>(start, snP, Zf8, dinv, b1, RUb2);

    // conv2: Z2b = bf16(Z2p + (H*r)@W2bot) ; out = u*H + (1-u)*tanh(...)
    k_gemm2b<<<GB, 256, 0, stream>>>(X, Hm, (const unsigned int*)RUb2, Wf2b, Z2p,
                                     (unsigned short*)Z2b);
    k_gather2<<<(NN + 15) / 16, 256, 0, stream>>>(start, snP, Z2b, dinv, b2, RUb2, Hm, out);
}